// Round 3
// baseline (893.201 us; speedup 1.0000x reference)
//
#include <hip/hip_runtime.h>
#include <hip/hip_fp16.h>

#define N_NODES 100000
#define N_EDGES 1600000
#define INP 16
#define EMB 32
#define ATTN 32
#define D0 48
#define RREL 200
#define NB 4
#define GAMMA_C 10.0f

#define SCAN_T 256
#define SCAN_I 4
#define SCAN_TILE 1024
#define NTILES ((N_NODES + SCAN_TILE - 1) / SCAN_TILE)   // 98

__device__ inline unsigned pack_h2(float a, float b) {
  __half2 h = __floats2half2_rn(a, b);
  return *reinterpret_cast<unsigned*>(&h);
}

// ---------------- node prep: h0 = concat(feat, embed[node_ids]); a1/a2 projections
__global__ __launch_bounds__(256) void k_node_prep(
    const float* __restrict__ feat, const int* __restrict__ node_ids,
    const float* __restrict__ embed,
    const float* __restrict__ A1w, const float* __restrict__ A1b,
    const float* __restrict__ A2w, const float* __restrict__ A2b,
    float* __restrict__ h0, float* __restrict__ a1, float* __restrict__ a2) {
  int n = blockIdx.x * blockDim.x + threadIdx.x;
  if (n >= N_NODES) return;
  float h[D0];
  const float4* f4 = reinterpret_cast<const float4*>(feat + (size_t)n * INP);
  #pragma unroll
  for (int i = 0; i < INP / 4; ++i) {
    float4 v = f4[i];
    h[4*i+0] = v.x; h[4*i+1] = v.y; h[4*i+2] = v.z; h[4*i+3] = v.w;
  }
  int nid = node_ids[n];
  const float4* e4 = reinterpret_cast<const float4*>(embed + (size_t)nid * EMB);
  #pragma unroll
  for (int i = 0; i < EMB / 4; ++i) {
    float4 v = e4[i];
    h[INP+4*i+0] = v.x; h[INP+4*i+1] = v.y; h[INP+4*i+2] = v.z; h[INP+4*i+3] = v.w;
  }
  float4* h04 = reinterpret_cast<float4*>(h0 + (size_t)n * D0);
  #pragma unroll
  for (int i = 0; i < D0 / 4; ++i)
    h04[i] = make_float4(h[4*i], h[4*i+1], h[4*i+2], h[4*i+3]);
  for (int o = 0; o < ATTN; ++o) {
    float acc = A1b[o];
    #pragma unroll
    for (int i = 0; i < D0; ++i) acc += h[i] * A1w[o * D0 + i];
    a1[(size_t)n * ATTN + o] = acc;
  }
  for (int o = 0; o < ATTN; ++o) {
    float acc = A2b[o];
    #pragma unroll
    for (int i = 0; i < D0; ++i) acc += h[i] * A2w[o * D0 + i];
    a2[(size_t)n * ATTN + o] = acc;
  }
}

// ---------------- CSR build
__global__ __launch_bounds__(256) void k_hist(const int* __restrict__ dst, int* __restrict__ cnt) {
  int e = blockIdx.x * blockDim.x + threadIdx.x;
  if (e >= N_EDGES) return;
  atomicAdd(&cnt[dst[e]], 1);
}

__global__ __launch_bounds__(SCAN_T) void k_scan1(const int* __restrict__ cnt,
                                                  int* __restrict__ excl, int* __restrict__ bsum) {
  __shared__ int sd[SCAN_T];
  int blk = blockIdx.x, tid = threadIdx.x;
  int base = blk * SCAN_TILE + tid * SCAN_I;
  int v[SCAN_I]; int s = 0;
  #pragma unroll
  for (int i = 0; i < SCAN_I; ++i) { int idx = base + i; v[i] = (idx < N_NODES) ? cnt[idx] : 0; s += v[i]; }
  sd[tid] = s; __syncthreads();
  for (int off = 1; off < SCAN_T; off <<= 1) {
    int t = (tid >= off) ? sd[tid - off] : 0;
    __syncthreads();
    sd[tid] += t;
    __syncthreads();
  }
  int run = sd[tid] - s;
  #pragma unroll
  for (int i = 0; i < SCAN_I; ++i) { int idx = base + i; if (idx < N_NODES) excl[idx] = run; run += v[i]; }
  if (tid == SCAN_T - 1) bsum[blk] = sd[tid];
}

__global__ __launch_bounds__(128) void k_scan2(int* __restrict__ bsum) {
  __shared__ int sd[128];
  int tid = threadIdx.x;
  int v = (tid < NTILES) ? bsum[tid] : 0;
  sd[tid] = v; __syncthreads();
  for (int off = 1; off < 128; off <<= 1) {
    int t = (tid >= off) ? sd[tid - off] : 0;
    __syncthreads();
    sd[tid] += t;
    __syncthreads();
  }
  if (tid < NTILES) bsum[tid] = sd[tid] - v;
}

__global__ __launch_bounds__(256) void k_scan3(int* __restrict__ row_start, int* __restrict__ cursor,
                                               const int* __restrict__ bsum) {
  int i = blockIdx.x * blockDim.x + threadIdx.x;
  if (i < N_NODES) {
    int v = row_start[i] + bsum[i / SCAN_TILE];
    row_start[i] = v; cursor[i] = v;
  }
  if (i == 0) row_start[N_NODES] = N_EDGES;
}

// scatter (src,typ) packed into dst-sorted order
__global__ __launch_bounds__(256) void k_scatter(
    const int* __restrict__ src, const int* __restrict__ dst, const int* __restrict__ typ,
    int* __restrict__ cursor, int2* __restrict__ s_st) {
  int e = blockIdx.x * blockDim.x + threadIdx.x;
  if (e >= N_EDGES) return;
  int d = dst[e];
  int pos = atomicAdd(&cursor[d], 1);
  s_st[pos] = make_int2(src[e], typ[e]);
}

// ---------------- alpha in dst-sorted order: one wave per node, half-wave per edge
__global__ __launch_bounds__(256) void k_alpha_seg(
    const int* __restrict__ row_start, const int2* __restrict__ s_st,
    const float* __restrict__ a1, const float* __restrict__ a2,
    const float* __restrict__ rel, float* __restrict__ s_alpha) {
  int wave = (blockIdx.x * blockDim.x + threadIdx.x) >> 6;
  int lane = threadIdx.x & 63;
  if (wave >= N_NODES) return;
  int beg = row_start[wave], end = row_start[wave + 1];
  int half = lane >> 5, c = lane & 31;
  float a2v = a2[(size_t)wave * ATTN + c];
  for (int e = beg + half; e < end; e += 2) {
    int2 st = s_st[e];
    float dx = a1[(size_t)st.x * ATTN + c] + rel[(size_t)st.y * ATTN + c] - a2v;
    float ss = dx * dx;
    #pragma unroll
    for (int m = 1; m <= 16; m <<= 1) ss += __shfl_xor(ss, m);
    if (c == 0) {
      float nrm = sqrtf(ss + 1e-12f);
      s_alpha[e] = 1.f / (1.f + __expf(nrm - GAMMA_C));
    }
  }
}

// ---------------- per-node layer: hb_h[n][c][b] fp16 = h@bases; selfbuf = h@sloop + bias
template <int DIN>
__global__ __launch_bounds__(256) void k_node_layer(
    const float* __restrict__ hin, const float* __restrict__ bases,
    const float* __restrict__ sloop, const float* __restrict__ bias,
    uint2* __restrict__ hb_h, float* __restrict__ selfbuf) {
  int n = blockIdx.x * blockDim.x + threadIdx.x;
  if (n >= N_NODES) return;
  float h[DIN];
  const float4* h4 = reinterpret_cast<const float4*>(hin + (size_t)n * DIN);
  #pragma unroll
  for (int i = 0; i < DIN / 4; ++i) {
    float4 v = h4[i];
    h[4*i+0] = v.x; h[4*i+1] = v.y; h[4*i+2] = v.z; h[4*i+3] = v.w;
  }
  float acc[NB][EMB];
  #pragma unroll
  for (int b = 0; b < NB; ++b)
    #pragma unroll
    for (int o = 0; o < EMB; ++o) acc[b][o] = 0.f;
  for (int i = 0; i < DIN; ++i) {
    float hv = h[i];
    #pragma unroll
    for (int b = 0; b < NB; ++b)
      #pragma unroll
      for (int o = 0; o < EMB; ++o) acc[b][o] += hv * bases[((b * DIN) + i) * EMB + o];
  }
  uint2* orow = hb_h + (size_t)n * EMB;
  #pragma unroll
  for (int c = 0; c < EMB; ++c) {
    uint2 v;
    v.x = pack_h2(acc[0][c], acc[1][c]);
    v.y = pack_h2(acc[2][c], acc[3][c]);
    orow[c] = v;
  }
  float s[EMB];
  #pragma unroll
  for (int o = 0; o < EMB; ++o) s[o] = bias[o];
  for (int i = 0; i < DIN; ++i) {
    float hv = h[i];
    #pragma unroll
    for (int o = 0; o < EMB; ++o) s[o] += hv * sloop[i * EMB + o];
  }
  float4* ob = reinterpret_cast<float4*>(selfbuf + (size_t)n * EMB);
  #pragma unroll
  for (int j = 0; j < EMB / 4; ++j)
    ob[j] = make_float4(s[4*j], s[4*j+1], s[4*j+2], s[4*j+3]);
}

// ---------------- segmented aggregation: one wave per dst node
__global__ __launch_bounds__(256) void k_edge_seg(
    const int* __restrict__ row_start,
    const int2* __restrict__ s_st, const float* __restrict__ s_alpha,
    const float* __restrict__ wcomp, const uint2* __restrict__ hb_h,
    const float* __restrict__ selfbuf, float* __restrict__ outp) {
  int wave = (blockIdx.x * blockDim.x + threadIdx.x) >> 6;
  int lane = threadIdx.x & 63;
  if (wave >= N_NODES) return;
  int beg = row_start[wave], end = row_start[wave + 1];
  int half = lane >> 5, c = lane & 31;
  float acc = 0.f;
  for (int e = beg + half; e < end; e += 2) {
    int2 st = s_st[e];
    float a = s_alpha[e];
    float4 w = *reinterpret_cast<const float4*>(wcomp + (size_t)st.y * NB);
    uint2 v = hb_h[(size_t)st.x * EMB + c];
    __half2 h01 = *reinterpret_cast<__half2*>(&v.x);
    __half2 h23 = *reinterpret_cast<__half2*>(&v.y);
    float2 f01 = __half22float2(h01);
    float2 f23 = __half22float2(h23);
    acc += a * (w.x * f01.x + w.y * f01.y + w.z * f23.x + w.w * f23.y);
  }
  acc += __shfl(acc, lane ^ 32);
  if (lane < 32) {
    size_t o = (size_t)wave * EMB + c;
    outp[o] = fmaxf(selfbuf[o] + acc, 0.f);
  }
}

extern "C" void kernel_launch(void* const* d_in, const int* in_sizes, int n_in,
                              void* d_out, int out_size, void* d_ws, size_t ws_size,
                              hipStream_t stream) {
  const float* feat     = (const float*)d_in[0];
  const int*   node_ids = (const int*)d_in[1];
  const int*   esrc     = (const int*)d_in[2];
  const int*   edst     = (const int*)d_in[3];
  const int*   etyp     = (const int*)d_in[4];
  const float* embed    = (const float*)d_in[5];
  const float* attn_rel = (const float*)d_in[6];
  const float* A1w = (const float*)d_in[7];
  const float* A1b = (const float*)d_in[8];
  const float* A2w = (const float*)d_in[9];
  const float* A2b = (const float*)d_in[10];
  const float* bases0 = (const float*)d_in[11];
  const float* wcomp0 = (const float*)d_in[12];
  const float* sloop0 = (const float*)d_in[13];
  const float* bias0  = (const float*)d_in[14];
  const float* bases1 = (const float*)d_in[15];
  const float* wcomp1 = (const float*)d_in[16];
  const float* sloop1 = (const float*)d_in[17];
  const float* bias1  = (const float*)d_in[18];
  const float* bases2 = (const float*)d_in[19];
  const float* wcomp2 = (const float*)d_in[20];
  const float* sloop2 = (const float*)d_in[21];
  const float* bias2  = (const float*)d_in[22];

  float* ws = (float*)d_ws;
  // [0, 4.8M)      h0 (read by L0 node layer; never reused after)
  // [4.8M, 8.0M)   s_st  (int2 x E)
  // [8.0M, 9.6M)   s_alpha (E)
  // [9.6M, 16.0M)  a1 (3.2M) | a2 (3.2M)  -> after alpha: HBh (half x N*128 = 6.4M floats)
  // [16.0M, 19.2M) selfbuf (N*32)
  // [19.2M, ...)   CSR metadata
  float* h0      = ws;
  int2*  s_st    = (int2*)(ws + 4800000);
  float* s_alpha = ws + 8000000;
  float* a1      = ws + 9600000;
  float* a2      = ws + 12800000;
  uint2* HBh     = (uint2*)(ws + 9600000);
  float* selfbuf = ws + 16000000;
  int* counts    = (int*)(ws + 19200000);   // N
  int* row_start = (int*)(ws + 19300000);   // N+1
  int* cursor    = (int*)(ws + 19400002);   // N
  int* bsum      = (int*)(ws + 19500002);   // NTILES
  float* out = (float*)d_out;

  dim3 blk(256);
  int nb_n = (N_NODES + 255) / 256;
  int nb_e = (N_EDGES + 255) / 256;
  int nb_w = (N_NODES * 64) / 256;

  k_node_prep<<<nb_n, blk, 0, stream>>>(feat, node_ids, embed, A1w, A1b, A2w, A2b, h0, a1, a2);

  hipMemsetAsync(counts, 0, N_NODES * sizeof(int), stream);
  k_hist<<<nb_e, blk, 0, stream>>>(edst, counts);
  k_scan1<<<NTILES, SCAN_T, 0, stream>>>(counts, row_start, bsum);
  k_scan2<<<1, 128, 0, stream>>>(bsum);
  k_scan3<<<nb_n, blk, 0, stream>>>(row_start, cursor, bsum);
  k_scatter<<<nb_e, blk, 0, stream>>>(esrc, edst, etyp, cursor, s_st);

  // alpha in sorted order (consumes a1/a2, then their region becomes HBh)
  k_alpha_seg<<<nb_w, blk, 0, stream>>>(row_start, s_st, a1, a2, attn_rel, s_alpha);

  // layer 0
  k_node_layer<D0><<<nb_n, blk, 0, stream>>>(h0, bases0, sloop0, bias0, HBh, selfbuf);
  k_edge_seg<<<nb_w, blk, 0, stream>>>(row_start, s_st, s_alpha, wcomp0, HBh, selfbuf, selfbuf);

  // layer 1
  k_node_layer<EMB><<<nb_n, blk, 0, stream>>>(selfbuf, bases1, sloop1, bias1, HBh, selfbuf);
  k_edge_seg<<<nb_w, blk, 0, stream>>>(row_start, s_st, s_alpha, wcomp1, HBh, selfbuf, selfbuf);

  // layer 2 -> d_out
  k_node_layer<EMB><<<nb_n, blk, 0, stream>>>(selfbuf, bases2, sloop2, bias2, HBh, selfbuf);
  k_edge_seg<<<nb_w, blk, 0, stream>>>(row_start, s_st, s_alpha, wcomp2, HBh, selfbuf, out);
}